// Round 1
// baseline (722.067 us; speedup 1.0000x reference)
//
#include <hip/hip_runtime.h>
#include <stdint.h>

// Problem constants
#define B_    4
#define T_    2048
#define C_    2048
#define H_    16
#define HKV_  8
#define D_    128
#define HD_   2048      // H_*D_
#define KVD_  1024      // HKV_*D_
#define NQKV_ 4096      // HD_+2*KVD_
#define BT_   8192      // B_*T_

typedef __bf16 bf16x8 __attribute__((ext_vector_type(8)));
typedef float  f32x4  __attribute__((ext_vector_type(4)));
typedef unsigned short u16;
typedef unsigned int   u32;

__device__ __forceinline__ u16 f2b(float f){
  union { float f; u32 u; } v; v.f = f;
  u32 r = v.u + 0x7FFFu + ((v.u >> 16) & 1u);   // RNE
  return (u16)(r >> 16);
}
__device__ __forceinline__ float b2f(u16 h){
  union { u32 u; float f; } v; v.u = ((u32)h) << 16;
  return v.f;
}

#define GLOAD16(src, dst) __builtin_amdgcn_global_load_lds( \
    (const __attribute__((address_space(1))) u32*)(src), \
    (__attribute__((address_space(3))) u32*)(dst), 16, 0, 0)

#define MFMA16(a,b,c) __builtin_amdgcn_mfma_f32_16x16x32_bf16((a), (b), (c), 0, 0, 0)

// ---------------------------------------------------------------------------
// fp32 -> bf16 bulk convert (x)
__global__ __launch_bounds__(256) void k_convx(const float* __restrict__ x, u16* __restrict__ xb){
  size_t i = ((size_t)blockIdx.x * 256 + threadIdx.x) * 4;
  float4 v = *(const float4*)(x + i);
  u32 w0 = (u32)f2b(v.x) | ((u32)f2b(v.y) << 16);
  u32 w1 = (u32)f2b(v.z) | ((u32)f2b(v.w) << 16);
  uint2 pk; pk.x = w0; pk.y = w1;
  *(uint2*)(xb + i) = pk;
}

// transpose + convert: src[K][N] fp32 -> dst[N][K] bf16 (64x64 LDS tiles)
__global__ __launch_bounds__(256) void k_wtrans(const float* __restrict__ src, u16* __restrict__ dst,
                                                int K, int N){
  __shared__ __attribute__((aligned(16))) u16 tile[64][68];
  int n0 = blockIdx.x * 64, k0 = blockIdx.y * 64;
  int r = threadIdx.x >> 4, c4 = (threadIdx.x & 15) * 4;
  #pragma unroll
  for (int rr = 0; rr < 4; ++rr){
    int kl = r + rr * 16;
    float4 v = *(const float4*)(src + (size_t)(k0 + kl) * N + n0 + c4);
    tile[kl][c4+0] = f2b(v.x); tile[kl][c4+1] = f2b(v.y);
    tile[kl][c4+2] = f2b(v.z); tile[kl][c4+3] = f2b(v.w);
  }
  __syncthreads();
  #pragma unroll
  for (int rr = 0; rr < 4; ++rr){
    int nl = r + rr * 16;
    u32 w0 = (u32)tile[c4+0][nl] | ((u32)tile[c4+1][nl] << 16);
    u32 w1 = (u32)tile[c4+2][nl] | ((u32)tile[c4+3][nl] << 16);
    uint2 pk; pk.x = w0; pk.y = w1;
    *(uint2*)(dst + (size_t)(n0 + nl) * K + k0 + c4) = pk;
  }
}

// combined bias vector [4096] = [bq | bk | bv]
__global__ void k_prep(const float* __restrict__ bq, const float* __restrict__ bk,
                       const float* __restrict__ bv, float* __restrict__ bias){
  int i = blockIdx.x * 256 + threadIdx.x;
  if (i < NQKV_)
    bias[i] = (i < HD_) ? bq[i] : (i < HD_ + KVD_ ? bk[i - HD_] : bv[i - HD_ - KVD_]);
}

// per-batch valid length from mask
__global__ void k_lens(const int* __restrict__ mask, int* __restrict__ lens){
  int b = blockIdx.x;
  int s = 0;
  for (int t = threadIdx.x; t < T_; t += 256) s += mask[b * T_ + t];
  #pragma unroll
  for (int d = 1; d < 64; d <<= 1) s += __shfl_xor(s, d);
  __shared__ int acc[4];
  if ((threadIdx.x & 63) == 0) acc[threadIdx.x >> 6] = s;
  __syncthreads();
  if (threadIdx.x == 0) lens[b] = acc[0] + acc[1] + acc[2] + acc[3];
}

// ---------------------------------------------------------------------------
// bf16 GEMM: C[M][N] = A[M][K] * BT[N][K]^T  (+bias), 128x128 tile, BK=64,
// m97 structure: global_load_lds width-16 staging, 4 waves, 4x4 16x16 frags/wave.
template<bool OUTF32>
__global__ __launch_bounds__(256) void k_gemm(const u16* __restrict__ A, const u16* __restrict__ BT,
                                              const float* __restrict__ bias, void* __restrict__ Cout,
                                              int M, int N, int K){
  __shared__ __attribute__((aligned(16))) u16 As[128 * 64];
  __shared__ __attribute__((aligned(16))) u16 Bs[128 * 64];
  int m0 = blockIdx.y * 128, n0 = blockIdx.x * 128;
  int lane = threadIdx.x & 63, w = threadIdx.x >> 6;
  int wr = w >> 1, wc = w & 1;
  int g = lane >> 4, lo = lane & 15;
  int srow = lane >> 3;            // 0..7 (8 rows per 1KB chunk)
  int sko  = (lane & 7) * 8;       // element offset within row
  f32x4 acc[4][4] = {};
  for (int k0 = 0; k0 < K; k0 += 64){
    #pragma unroll
    for (int c = 0; c < 4; ++c){
      int ch = w * 4 + c;
      int row = ch * 8 + srow;
      GLOAD16(A  + (size_t)(m0 + row) * K + k0 + sko, &As[ch * 512]);
      GLOAD16(BT + (size_t)(n0 + row) * K + k0 + sko, &Bs[ch * 512]);
    }
    __syncthreads();
    #pragma unroll
    for (int kk = 0; kk < 2; ++kk){
      bf16x8 af[4], bfv[4];
      #pragma unroll
      for (int i = 0; i < 4; ++i)
        af[i] = *(const bf16x8*)&As[(wr*64 + i*16 + lo) * 64 + kk*32 + g*8];
      #pragma unroll
      for (int j = 0; j < 4; ++j)
        bfv[j] = *(const bf16x8*)&Bs[(wc*64 + j*16 + lo) * 64 + kk*32 + g*8];
      #pragma unroll
      for (int i = 0; i < 4; ++i)
        #pragma unroll
        for (int j = 0; j < 4; ++j)
          acc[i][j] = MFMA16(af[i], bfv[j], acc[i][j]);
    }
    __syncthreads();
  }
  #pragma unroll
  for (int i = 0; i < 4; ++i){
    #pragma unroll
    for (int j = 0; j < 4; ++j){
      #pragma unroll
      for (int r = 0; r < 4; ++r){
        int row = m0 + wr*64 + i*16 + g*4 + r;
        int col = n0 + wc*64 + j*16 + lo;
        float v = acc[i][j][r] + (bias ? bias[col] : 0.0f);
        if (OUTF32) ((float*)Cout)[(size_t)row * N + col] = v;
        else        ((u16*)Cout)[(size_t)row * N + col] = f2b(v);
      }
    }
  }
}

// ---------------------------------------------------------------------------
// Per-(b,t) RMSNorm + mRoPE for q (16 heads) and k (8 heads, masked).
// One wave per head-row of 128 (2 elems/lane), 4 waves x 6 heads.
__global__ __launch_bounds__(256) void k_rmsrope(const u16* __restrict__ qkv,
    const float* __restrict__ cosp, const float* __restrict__ sinp,
    const int* __restrict__ mask, const float* __restrict__ gq, const float* __restrict__ gk,
    u16* __restrict__ qrot, u16* __restrict__ krot){
  int tok = blockIdx.x;
  int b = tok >> 11, t = tok & (T_ - 1);
  int lane = threadIdx.x & 63, w = threadIdx.x >> 6;
  int dl = (lane & 31) * 2;                 // index into the 64-entry half table
  int a0 = dl < 24 ? 0 : (dl < 44 ? 1 : 2);
  int a1 = (dl + 1) < 24 ? 0 : ((dl + 1) < 44 ? 1 : 2);
  size_t cb = ((size_t)b * T_ + t) * 64;
  const size_t AX = (size_t)B_ * T_ * 64;
  float ce0 = cosp[(size_t)a0 * AX + cb + dl],     se0 = sinp[(size_t)a0 * AX + cb + dl];
  float ce1 = cosp[(size_t)a1 * AX + cb + dl + 1], se1 = sinp[(size_t)a1 * AX + cb + dl + 1];
  float sgn = (lane < 32) ? -1.f : 1.f;
  float mk = (float)mask[b * T_ + t];
  const u16* base = qkv + (size_t)tok * NQKV_;
  for (int head = w; head < H_ + HKV_; head += 4){
    bool isq = head < H_;
    int off = isq ? head * D_ : HD_ + (head - H_) * D_;
    u32 pr = *(const u32*)(base + off + lane * 2);
    float x0 = b2f((u16)(pr & 0xFFFF)), x1 = b2f((u16)(pr >> 16));
    float ss = x0*x0 + x1*x1;
    #pragma unroll
    for (int d = 1; d < 64; d <<= 1) ss += __shfl_xor(ss, d);
    float rinv = rsqrtf(ss * (1.0f / 128.0f) + 1e-6f);
    const float* gg = isq ? gq : gk;
    float2 gv = *(const float2*)(gg + lane * 2);
    float n0 = gv.x * x0 * rinv, n1 = gv.y * x1 * rinv;
    float p0 = __shfl_xor(n0, 32), p1 = __shfl_xor(n1, 32);
    float o0 = n0 * ce0 + sgn * p0 * se0;
    float o1 = n1 * ce1 + sgn * p1 * se1;
    u16* dst;
    if (isq){
      dst = qrot + ((size_t)(b * H_ + head) * T_ + t) * D_;
    } else {
      o0 *= mk; o1 *= mk;
      dst = krot + ((size_t)(b * HKV_ + (head - H_)) * T_ + t) * D_;
    }
    u32 ow = (u32)f2b(o0) | ((u32)f2b(o1) << 16);
    *(u32*)(dst + lane * 2) = ow;
  }
}

// V transpose: qkv[b,t, 3072 + h*128 + d] (masked) -> vt[b,h,d,t]
__global__ __launch_bounds__(256) void k_vtrans(const u16* __restrict__ qkv, const int* __restrict__ mask,
                                                u16* __restrict__ vt){
  int t0 = blockIdx.x * 64, d0 = blockIdx.y * 64;
  int bh = blockIdx.z;
  int b = bh >> 3, hk = bh & 7;
  __shared__ __attribute__((aligned(16))) u16 tile[64][68];
  int r = threadIdx.x >> 4, c4 = (threadIdx.x & 15) * 4;
  #pragma unroll
  for (int rr = 0; rr < 4; ++rr){
    int tl = r + rr * 16;
    int t = t0 + tl;
    u16 mz = (u16)(mask[b * T_ + t] ? 0xFFFFu : 0u);
    ushort4 v = *(const ushort4*)(qkv + (size_t)(b * T_ + t) * NQKV_ + HD_ + KVD_ + hk * D_ + d0 + c4);
    tile[tl][c4+0] = (u16)(v.x & mz); tile[tl][c4+1] = (u16)(v.y & mz);
    tile[tl][c4+2] = (u16)(v.z & mz); tile[tl][c4+3] = (u16)(v.w & mz);
  }
  __syncthreads();
  #pragma unroll
  for (int rr = 0; rr < 4; ++rr){
    int dn = r + rr * 16;
    u32 w0 = (u32)tile[c4+0][dn] | ((u32)tile[c4+1][dn] << 16);
    u32 w1 = (u32)tile[c4+2][dn] | ((u32)tile[c4+3][dn] << 16);
    uint2 pk; pk.x = w0; pk.y = w1;
    *(uint2*)(vt + ((size_t)bh * D_ + d0 + dn) * T_ + t0 + c4) = pk;
  }
}

// ---------------------------------------------------------------------------
// Flash attention (causal, GQA 2:1). Block = 4 waves, 64 q-rows (16/wave),
// K-tiles of 64. Ks[64][136] (padded), Vs=V^T[128][72] (padded), per-wave P LDS.
__global__ __launch_bounds__(256) void k_attn(const u16* __restrict__ qrot, const u16* __restrict__ krot,
                                              const u16* __restrict__ vt, const int* __restrict__ lens,
                                              u16* __restrict__ ao){
  int q0 = blockIdx.x * 64;
  int h = blockIdx.y, b = blockIdx.z;
  int hk = h >> 1;
  int lane = threadIdx.x & 63, w = threadIdx.x >> 6, tid = threadIdx.x;
  int g = lane >> 4, lo = lane & 15;
  int len = lens[b];
  __shared__ __attribute__((aligned(16))) u16 Ks[64 * 136];
  __shared__ __attribute__((aligned(16))) u16 Vs[128 * 72];
  __shared__ __attribute__((aligned(16))) u16 Ps[4 * 16 * 72];
  const u16* qbase = qrot + ((size_t)(b * H_ + h) * T_ + q0 + w * 16 + lo) * D_ + g * 8;
  bf16x8 qf[4];
  #pragma unroll
  for (int kk = 0; kk < 4; ++kk) qf[kk] = *(const bf16x8*)(qbase + kk * 32);
  float mrow[4] = {-1e30f, -1e30f, -1e30f, -1e30f};
  float lrow[4] = {0.f, 0.f, 0.f, 0.f};
  f32x4 o[8] = {};
  const u16* kbase = krot + (size_t)(b * HKV_ + hk) * T_ * D_;
  const u16* vbase = vt   + (size_t)(b * HKV_ + hk) * D_ * T_;
  const float scale = 0.08838834764831845f;   // 1/sqrt(128)
  int ks_row = tid >> 2, ks_seg = (tid & 3) * 32;
  int vs_row = tid >> 1, vs_seg = (tid & 1) * 32;
  for (int j0 = 0; j0 <= q0 && j0 < len; j0 += 64){
    {  // stage K tile [64][128] -> Ks (padded 136)
      const u16* s1 = kbase + (size_t)(j0 + ks_row) * D_ + ks_seg;
      u16* d1 = &Ks[ks_row * 136 + ks_seg];
      #pragma unroll
      for (int q = 0; q < 4; ++q) *(uint4*)(d1 + q * 8) = *(const uint4*)(s1 + q * 8);
    }
    {  // stage V^T tile [128][64] -> Vs (padded 72)
      const u16* s2 = vbase + (size_t)vs_row * T_ + j0 + vs_seg;
      u16* d2 = &Vs[vs_row * 72 + vs_seg];
      #pragma unroll
      for (int q = 0; q < 4; ++q) *(uint4*)(d2 + q * 8) = *(const uint4*)(s2 + q * 8);
    }
    __syncthreads();
    // QK^T: S[16q x 64k] per wave
    f32x4 s[4] = {};
    #pragma unroll
    for (int kk = 0; kk < 4; ++kk){
      #pragma unroll
      for (int nf = 0; nf < 4; ++nf){
        bf16x8 kf = *(const bf16x8*)&Ks[(nf * 16 + lo) * 136 + kk * 32 + g * 8];
        s[nf] = MFMA16(qf[kk], kf, s[nf]);
      }
    }
    // online softmax (rows live as 4 per 16-lane group)
    float p[4][4];
    #pragma unroll
    for (int r = 0; r < 4; ++r){
      int qrow = q0 + w * 16 + g * 4 + r;
      float mx = -1e30f;
      #pragma unroll
      for (int nf = 0; nf < 4; ++nf){
        float v = s[nf][r] * scale;
        int j = j0 + nf * 16 + lo;
        if (j > qrow || j >= len) v = -1e30f;
        p[nf][r] = v;
        mx = fmaxf(mx, v);
      }
      #pragma unroll
      for (int d = 1; d < 16; d <<= 1) mx = fmaxf(mx, __shfl_xor(mx, d));
      float mn = fmaxf(mrow[r], mx);
      float sum = 0.f;
      #pragma unroll
      for (int nf = 0; nf < 4; ++nf){
        float e = __expf(p[nf][r] - mn);
        p[nf][r] = e;
        sum += e;
      }
      #pragma unroll
      for (int d = 1; d < 16; d <<= 1) sum += __shfl_xor(sum, d);
      float alpha = __expf(mrow[r] - mn);
      lrow[r] = lrow[r] * alpha + sum;
      mrow[r] = mn;
      #pragma unroll
      for (int df = 0; df < 8; ++df) o[df][r] *= alpha;
    }
    // P -> per-wave LDS (bf16), padded stride 72
    #pragma unroll
    for (int nf = 0; nf < 4; ++nf)
      #pragma unroll
      for (int r = 0; r < 4; ++r)
        Ps[w * 1152 + (g * 4 + r) * 72 + nf * 16 + lo] = f2b(p[nf][r]);
    asm volatile("s_waitcnt lgkmcnt(0)" ::: "memory");
    // PV: O[16q x 128d] += P[16x64] * V[64x128]
    #pragma unroll
    for (int kk2 = 0; kk2 < 2; ++kk2){
      bf16x8 pf = *(const bf16x8*)&Ps[w * 1152 + lo * 72 + kk2 * 32 + g * 8];
      #pragma unroll
      for (int df = 0; df < 8; ++df){
        bf16x8 vf = *(const bf16x8*)&Vs[(df * 16 + lo) * 72 + kk2 * 32 + g * 8];
        o[df] = MFMA16(pf, vf, o[df]);
      }
    }
    __syncthreads();
  }
  // epilogue: divide by l, write bf16 [B*T][H*D]
  #pragma unroll
  for (int df = 0; df < 8; ++df){
    #pragma unroll
    for (int r = 0; r < 4; ++r){
      int qrow = q0 + w * 16 + g * 4 + r;
      float ov = o[df][r] / lrow[r];
      ao[((size_t)(b * T_ + qrow)) * HD_ + h * D_ + df * 16 + lo] = f2b(ov);
    }
  }
}

// ---------------------------------------------------------------------------
extern "C" void kernel_launch(void* const* d_in, const int* in_sizes, int n_in,
                              void* d_out, int out_size, void* d_ws, size_t ws_size,
                              hipStream_t stream) {
  (void)in_sizes; (void)n_in; (void)out_size; (void)ws_size;
  const float* x    = (const float*)d_in[0];
  const float* cosp = (const float*)d_in[1];
  const float* sinp = (const float*)d_in[2];
  const int*   mask = (const int*)d_in[3];
  const float* Wq   = (const float*)d_in[4];
  const float* bq   = (const float*)d_in[5];
  const float* Wk   = (const float*)d_in[6];
  const float* bk   = (const float*)d_in[7];
  const float* Wv   = (const float*)d_in[8];
  const float* bv   = (const float*)d_in[9];
  const float* gq   = (const float*)d_in[10];
  const float* gk   = (const float*)d_in[11];
  const float* Wo   = (const float*)d_in[12];

  char* ws = (char*)d_ws;
  const size_t MB = 1024 * 1024;
  u16*   XB    = (u16*)(ws);                 // 32MB  x as bf16 [8192][2048]
  u16*   WQKVT = (u16*)(ws + 32  * MB);      // 16MB  [Wq;Wk;Wv]^T bf16 [4096][2048]
  u16*   WOT   = (u16*)(ws + 48  * MB);      //  8MB  Wo^T bf16 [2048][2048]
  u16*   QKV   = (u16*)(ws + 56  * MB);      // 64MB  qkv bf16 [8192][4096]
  u16*   QROT  = (u16*)(ws + 120 * MB);      // 32MB  q rot bf16 [B][H][T][D]
  u16*   KROT  = (u16*)(ws + 152 * MB);      // 16MB  k rot bf16 [B][HKV][T][D]
  u16*   VT    = (u16*)(ws + 168 * MB);      // 16MB  v^T bf16 [B][HKV][D][T]
  u16*   AO    = (u16*)(ws + 184 * MB);      // 32MB  attn out bf16 [8192][2048]
  float* BIAS  = (float*)(ws + 216 * MB);    // 16KB
  int*   LENS  = (int*)(ws + 216 * MB + 65536);

  k_convx<<<16384, 256, 0, stream>>>(x, XB);
  k_wtrans<<<dim3(32, 32), 256, 0, stream>>>(Wq, WQKVT, C_, HD_);
  k_wtrans<<<dim3(16, 32), 256, 0, stream>>>(Wk, WQKVT + (size_t)HD_ * C_, C_, KVD_);
  k_wtrans<<<dim3(16, 32), 256, 0, stream>>>(Wv, WQKVT + (size_t)(HD_ + KVD_) * C_, C_, KVD_);
  k_wtrans<<<dim3(32, 32), 256, 0, stream>>>(Wo, WOT, HD_, C_);
  k_prep<<<16, 256, 0, stream>>>(bq, bk, bv, BIAS);
  k_lens<<<4, 256, 0, stream>>>(mask, LENS);

  // qkv = x @ [Wq|Wk|Wv] + bias   (bf16 out)
  k_gemm<false><<<dim3(NQKV_ / 128, BT_ / 128), 256, 0, stream>>>(XB, WQKVT, BIAS, QKV, BT_, NQKV_, C_);
  // RMSNorm + mRoPE, repack q/k
  k_rmsrope<<<BT_, 256, 0, stream>>>(QKV, cosp, sinp, mask, gq, gk, QROT, KROT);
  // v -> v^T (masked)
  k_vtrans<<<dim3(T_ / 64, D_ / 64, B_ * HKV_), 256, 0, stream>>>(QKV, mask, VT);
  // causal GQA flash attention
  k_attn<<<dim3(T_ / 64, H_, B_), 256, 0, stream>>>(QROT, KROT, VT, LENS, AO);
  // out = AO @ Wo   (fp32 out)
  k_gemm<true><<<dim3(C_ / 128, BT_ / 128), 256, 0, stream>>>(AO, WOT, nullptr, d_out, BT_, C_, HD_);
}

// Round 2
// 627.335 us; speedup vs baseline: 1.1510x; 1.1510x over previous
//
#include <hip/hip_runtime.h>
#include <stdint.h>

// Problem constants
#define B_    4
#define T_    2048
#define C_    2048
#define H_    16
#define HKV_  8
#define D_    128
#define HD_   2048      // H_*D_
#define KVD_  1024      // HKV_*D_
#define NQKV_ 4096      // HD_+2*KVD_
#define BT_   8192      // B_*T_

typedef __bf16 bf16x8 __attribute__((ext_vector_type(8)));
typedef float  f32x4  __attribute__((ext_vector_type(4)));
typedef unsigned short u16;
typedef unsigned int   u32;

__device__ __forceinline__ u16 f2b(float f){
  union { float f; u32 u; } v; v.f = f;
  u32 r = v.u + 0x7FFFu + ((v.u >> 16) & 1u);   // RNE
  return (u16)(r >> 16);
}
__device__ __forceinline__ float b2f(u16 h){
  union { u32 u; float f; } v; v.u = ((u32)h) << 16;
  return v.f;
}

#define GLOAD16(src, dst) __builtin_amdgcn_global_load_lds( \
    (const __attribute__((address_space(1))) u32*)(src), \
    (__attribute__((address_space(3))) u32*)(dst), 16, 0, 0)

#define MFMA16(a,b,c) __builtin_amdgcn_mfma_f32_16x16x32_bf16((a), (b), (c), 0, 0, 0)

// ---------------------------------------------------------------------------
// fp32 -> bf16 bulk convert (x)
__global__ __launch_bounds__(256) void k_convx(const float* __restrict__ x, u16* __restrict__ xb){
  size_t i = ((size_t)blockIdx.x * 256 + threadIdx.x) * 4;
  float4 v = *(const float4*)(x + i);
  u32 w0 = (u32)f2b(v.x) | ((u32)f2b(v.y) << 16);
  u32 w1 = (u32)f2b(v.z) | ((u32)f2b(v.w) << 16);
  uint2 pk; pk.x = w0; pk.y = w1;
  *(uint2*)(xb + i) = pk;
}

// transpose + convert: src[K][N] fp32 -> dst[N][K] bf16 (64x64 LDS tiles)
__global__ __launch_bounds__(256) void k_wtrans(const float* __restrict__ src, u16* __restrict__ dst,
                                                int K, int N){
  __shared__ __attribute__((aligned(16))) u16 tile[64][68];
  int n0 = blockIdx.x * 64, k0 = blockIdx.y * 64;
  int r = threadIdx.x >> 4, c4 = (threadIdx.x & 15) * 4;
  #pragma unroll
  for (int rr = 0; rr < 4; ++rr){
    int kl = r + rr * 16;
    float4 v = *(const float4*)(src + (size_t)(k0 + kl) * N + n0 + c4);
    tile[kl][c4+0] = f2b(v.x); tile[kl][c4+1] = f2b(v.y);
    tile[kl][c4+2] = f2b(v.z); tile[kl][c4+3] = f2b(v.w);
  }
  __syncthreads();
  #pragma unroll
  for (int rr = 0; rr < 4; ++rr){
    int nl = r + rr * 16;
    u32 w0 = (u32)tile[c4+0][nl] | ((u32)tile[c4+1][nl] << 16);
    u32 w1 = (u32)tile[c4+2][nl] | ((u32)tile[c4+3][nl] << 16);
    uint2 pk; pk.x = w0; pk.y = w1;
    *(uint2*)(dst + (size_t)(n0 + nl) * K + k0 + c4) = pk;
  }
}

// combined bias vector [4096] = [bq | bk | bv]
__global__ void k_prep(const float* __restrict__ bq, const float* __restrict__ bk,
                       const float* __restrict__ bv, float* __restrict__ bias){
  int i = blockIdx.x * 256 + threadIdx.x;
  if (i < NQKV_)
    bias[i] = (i < HD_) ? bq[i] : (i < HD_ + KVD_ ? bk[i - HD_] : bv[i - HD_ - KVD_]);
}

// per-batch valid length from mask
__global__ void k_lens(const int* __restrict__ mask, int* __restrict__ lens){
  int b = blockIdx.x;
  int s = 0;
  for (int t = threadIdx.x; t < T_; t += 256) s += mask[b * T_ + t];
  #pragma unroll
  for (int d = 1; d < 64; d <<= 1) s += __shfl_xor(s, d);
  __shared__ int acc[4];
  if ((threadIdx.x & 63) == 0) acc[threadIdx.x >> 6] = s;
  __syncthreads();
  if (threadIdx.x == 0) lens[b] = acc[0] + acc[1] + acc[2] + acc[3];
}

// ---------------------------------------------------------------------------
// bf16 GEMM: C[M][N] = A[M][K] * BT[N][K]^T  (+bias), 128x128 tile, BK=64,
// m97 structure: global_load_lds width-16 staging, 4 waves, 4x4 16x16 frags/wave.
template<bool OUTF32>
__global__ __launch_bounds__(256) void k_gemm(const u16* __restrict__ A, const u16* __restrict__ BT,
                                              const float* __restrict__ bias, void* __restrict__ Cout,
                                              int M, int N, int K){
  __shared__ __attribute__((aligned(16))) u16 As[128 * 64];
  __shared__ __attribute__((aligned(16))) u16 Bs[128 * 64];
  int m0 = blockIdx.y * 128, n0 = blockIdx.x * 128;
  int lane = threadIdx.x & 63, w = threadIdx.x >> 6;
  int wr = w >> 1, wc = w & 1;
  int g = lane >> 4, lo = lane & 15;
  int srow = lane >> 3;            // 0..7 (8 rows per 1KB chunk)
  int sko  = (lane & 7) * 8;       // element offset within row
  f32x4 acc[4][4] = {};
  for (int k0 = 0; k0 < K; k0 += 64){
    #pragma unroll
    for (int c = 0; c < 4; ++c){
      int ch = w * 4 + c;
      int row = ch * 8 + srow;
      GLOAD16(A  + (size_t)(m0 + row) * K + k0 + sko, &As[ch * 512]);
      GLOAD16(BT + (size_t)(n0 + row) * K + k0 + sko, &Bs[ch * 512]);
    }
    __syncthreads();
    #pragma unroll
    for (int kk = 0; kk < 2; ++kk){
      bf16x8 af[4], bfv[4];
      #pragma unroll
      for (int i = 0; i < 4; ++i)
        af[i] = *(const bf16x8*)&As[(wr*64 + i*16 + lo) * 64 + kk*32 + g*8];
      #pragma unroll
      for (int j = 0; j < 4; ++j)
        bfv[j] = *(const bf16x8*)&Bs[(wc*64 + j*16 + lo) * 64 + kk*32 + g*8];
      #pragma unroll
      for (int i = 0; i < 4; ++i)
        #pragma unroll
        for (int j = 0; j < 4; ++j)
          acc[i][j] = MFMA16(af[i], bfv[j], acc[i][j]);
    }
    __syncthreads();
  }
  #pragma unroll
  for (int i = 0; i < 4; ++i){
    #pragma unroll
    for (int j = 0; j < 4; ++j){
      #pragma unroll
      for (int r = 0; r < 4; ++r){
        int row = m0 + wr*64 + i*16 + g*4 + r;
        int col = n0 + wc*64 + j*16 + lo;
        float v = acc[i][j][r] + (bias ? bias[col] : 0.0f);
        if (OUTF32) ((float*)Cout)[(size_t)row * N + col] = v;
        else        ((u16*)Cout)[(size_t)row * N + col] = f2b(v);
      }
    }
  }
}

// ---------------------------------------------------------------------------
// Per-(b,t) RMSNorm + mRoPE for q (16 heads) and k (8 heads, masked).
// Q output is pre-scaled by (1/sqrt(D)) * log2(e) so attention can use exp2.
__global__ __launch_bounds__(256) void k_rmsrope(const u16* __restrict__ qkv,
    const float* __restrict__ cosp, const float* __restrict__ sinp,
    const int* __restrict__ mask, const float* __restrict__ gq, const float* __restrict__ gk,
    u16* __restrict__ qrot, u16* __restrict__ krot){
  const float QS = 0.08838834764831845f * 1.4426950408889634f;  // scale * log2e
  int tok = blockIdx.x;
  int b = tok >> 11, t = tok & (T_ - 1);
  int lane = threadIdx.x & 63, w = threadIdx.x >> 6;
  int dl = (lane & 31) * 2;                 // index into the 64-entry half table
  int a0 = dl < 24 ? 0 : (dl < 44 ? 1 : 2);
  int a1 = (dl + 1) < 24 ? 0 : ((dl + 1) < 44 ? 1 : 2);
  size_t cb = ((size_t)b * T_ + t) * 64;
  const size_t AX = (size_t)B_ * T_ * 64;
  float ce0 = cosp[(size_t)a0 * AX + cb + dl],     se0 = sinp[(size_t)a0 * AX + cb + dl];
  float ce1 = cosp[(size_t)a1 * AX + cb + dl + 1], se1 = sinp[(size_t)a1 * AX + cb + dl + 1];
  float sgn = (lane < 32) ? -1.f : 1.f;
  float mk = (float)mask[b * T_ + t];
  const u16* base = qkv + (size_t)tok * NQKV_;
  for (int head = w; head < H_ + HKV_; head += 4){
    bool isq = head < H_;
    int off = isq ? head * D_ : HD_ + (head - H_) * D_;
    u32 pr = *(const u32*)(base + off + lane * 2);
    float x0 = b2f((u16)(pr & 0xFFFF)), x1 = b2f((u16)(pr >> 16));
    float ss = x0*x0 + x1*x1;
    #pragma unroll
    for (int d = 1; d < 64; d <<= 1) ss += __shfl_xor(ss, d);
    float rinv = rsqrtf(ss * (1.0f / 128.0f) + 1e-6f);
    const float* gg = isq ? gq : gk;
    float2 gv = *(const float2*)(gg + lane * 2);
    float n0 = gv.x * x0 * rinv, n1 = gv.y * x1 * rinv;
    float p0 = __shfl_xor(n0, 32), p1 = __shfl_xor(n1, 32);
    float o0 = n0 * ce0 + sgn * p0 * se0;
    float o1 = n1 * ce1 + sgn * p1 * se1;
    u16* dst;
    if (isq){
      o0 *= QS; o1 *= QS;
      dst = qrot + ((size_t)(b * H_ + head) * T_ + t) * D_;
    } else {
      o0 *= mk; o1 *= mk;
      dst = krot + ((size_t)(b * HKV_ + (head - H_)) * T_ + t) * D_;
    }
    u32 ow = (u32)f2b(o0) | ((u32)f2b(o1) << 16);
    *(u32*)(dst + lane * 2) = ow;
  }
}

// V transpose: qkv[b,t, 3072 + h*128 + d] (masked) -> vt[b,h,d,t]
__global__ __launch_bounds__(256) void k_vtrans(const u16* __restrict__ qkv, const int* __restrict__ mask,
                                                u16* __restrict__ vt){
  int t0 = blockIdx.x * 64, d0 = blockIdx.y * 64;
  int bh = blockIdx.z;
  int b = bh >> 3, hk = bh & 7;
  __shared__ __attribute__((aligned(16))) u16 tile[64][68];
  int r = threadIdx.x >> 4, c4 = (threadIdx.x & 15) * 4;
  #pragma unroll
  for (int rr = 0; rr < 4; ++rr){
    int tl = r + rr * 16;
    int t = t0 + tl;
    u16 mz = (u16)(mask[b * T_ + t] ? 0xFFFFu : 0u);
    ushort4 v = *(const ushort4*)(qkv + (size_t)(b * T_ + t) * NQKV_ + HD_ + KVD_ + hk * D_ + d0 + c4);
    tile[tl][c4+0] = (u16)(v.x & mz); tile[tl][c4+1] = (u16)(v.y & mz);
    tile[tl][c4+2] = (u16)(v.z & mz); tile[tl][c4+3] = (u16)(v.w & mz);
  }
  __syncthreads();
  #pragma unroll
  for (int rr = 0; rr < 4; ++rr){
    int dn = r + rr * 16;
    u32 w0 = (u32)tile[c4+0][dn] | ((u32)tile[c4+1][dn] << 16);
    u32 w1 = (u32)tile[c4+2][dn] | ((u32)tile[c4+3][dn] << 16);
    uint2 pk; pk.x = w0; pk.y = w1;
    *(uint2*)(vt + ((size_t)bh * D_ + d0 + dn) * T_ + t0 + c4) = pk;
  }
}

// ---------------------------------------------------------------------------
// Flash attention (causal, GQA 2:1), swapped-QK^T structure.
// Block = 4 waves, 64 q-rows (16/wave). K-tiles of 64.
// S^T = mfma(K,Q): lane (g,lo) holds S[k = nf*16+g*4+r][q = lo] -> softmax row
// stats are lane-local + 2 shfl_xor. P^T -> PV A-frag rebuilt in-register via
// 8 packs + 16 ds_bpermute (no P LDS buffer).
__global__ __launch_bounds__(256) void k_attn(const u16* __restrict__ qrot, const u16* __restrict__ krot,
                                              const u16* __restrict__ vt, const int* __restrict__ lens,
                                              u16* __restrict__ ao){
  // XCD-aware decode: 2048 blocks, 8 XCDs, 256 consecutive work-items per XCD
  // so the 32 q-tile blocks sharing one (b,h) KV panel colocate on one XCD L2.
  int fid = blockIdx.x;
  int gs = (fid % 8) * 256 + fid / 8;
  int q0 = (gs & 31) * 64;
  int h = (gs >> 5) & 15, b = gs >> 9;
  int hk = h >> 1;
  int lane = threadIdx.x & 63, w = threadIdx.x >> 6, tid = threadIdx.x;
  int g = lane >> 4, lo = lane & 15;
  int len = lens[b];
  __shared__ __attribute__((aligned(16))) u16 Ks[64 * 136];
  __shared__ __attribute__((aligned(16))) u16 Vs[128 * 72];
  const u16* qbase = qrot + ((size_t)(b * H_ + h) * T_ + q0 + w * 16 + lo) * D_ + g * 8;
  bf16x8 qf[4];
  #pragma unroll
  for (int kk = 0; kk < 4; ++kk) qf[kk] = *(const bf16x8*)(qbase + kk * 32);
  float m_run = -1e30f, l_run = 0.f;
  f32x4 o[8] = {};
  int qrow = q0 + w * 16 + lo;         // this lane's softmax row
  const u16* kbase = krot + (size_t)(b * HKV_ + hk) * T_ * D_;
  const u16* vbase = vt   + (size_t)(b * HKV_ + hk) * D_ * T_;
  int ks_row = tid >> 2, ks_seg = (tid & 3) * 32;
  int vs_row = tid >> 1, vs_seg = (tid & 1) * 32;
  int srcA = ((lane & 16) * 2 + (lane & 15)) * 4;   // bpermute byte index
  int srcB = srcA + 64;
  bool hi = lane >= 32;
  for (int j0 = 0; j0 <= q0 && j0 < len; j0 += 64){
    {  // stage K tile [64][128] -> Ks (padded 136)
      const u16* s1 = kbase + (size_t)(j0 + ks_row) * D_ + ks_seg;
      u16* d1 = &Ks[ks_row * 136 + ks_seg];
      #pragma unroll
      for (int q = 0; q < 4; ++q) *(uint4*)(d1 + q * 8) = *(const uint4*)(s1 + q * 8);
    }
    {  // stage V^T tile [128][64] -> Vs (padded 72)
      const u16* s2 = vbase + (size_t)vs_row * T_ + j0 + vs_seg;
      u16* d2 = &Vs[vs_row * 72 + vs_seg];
      #pragma unroll
      for (int q = 0; q < 4; ++q) *(uint4*)(d2 + q * 8) = *(const uint4*)(s2 + q * 8);
    }
    __syncthreads();
    // S^T = K * Q^T : st[nf][r] = S[k=nf*16+g*4+r][q=lo]  (already scaled+log2e)
    f32x4 st[4] = {};
    #pragma unroll
    for (int kk = 0; kk < 4; ++kk){
      #pragma unroll
      for (int nf = 0; nf < 4; ++nf){
        bf16x8 kf = *(const bf16x8*)&Ks[(nf * 16 + lo) * 136 + kk * 32 + g * 8];
        st[nf] = MFMA16(kf, qf[kk], st[nf]);
      }
    }
    // wait: kf above uses lo as K-row (A-frag rows), correct for swapped mfma.
    bool needmask = (j0 == q0) || (j0 + 64 > len);
    if (needmask){
      #pragma unroll
      for (int nf = 0; nf < 4; ++nf)
        #pragma unroll
        for (int r = 0; r < 4; ++r){
          int k = j0 + nf * 16 + g * 4 + r;
          if (k > qrow || k >= len) st[nf][r] = -1e30f;
        }
    }
    // row max: in-register tree + cross-group (lanes lo, lo+16, lo+32, lo+48)
    float mf[4];
    #pragma unroll
    for (int nf = 0; nf < 4; ++nf)
      mf[nf] = fmaxf(fmaxf(st[nf][0], st[nf][1]), fmaxf(st[nf][2], st[nf][3]));
    float mx = fmaxf(fmaxf(mf[0], mf[1]), fmaxf(mf[2], mf[3]));
    mx = fmaxf(mx, __shfl_xor(mx, 16));
    mx = fmaxf(mx, __shfl_xor(mx, 32));
    bool skip = __all(mx <= m_run);       // T13 defer: no new max anywhere
    float mn = skip ? m_run : fmaxf(m_run, mx);
    // p = exp2(s - mn), sum
    float sf[4];
    #pragma unroll
    for (int nf = 0; nf < 4; ++nf){
      #pragma unroll
      for (int r = 0; r < 4; ++r){
        float e = exp2f(st[nf][r] - mn);
        st[nf][r] = e;
      }
      sf[nf] = (st[nf][0] + st[nf][1]) + (st[nf][2] + st[nf][3]);
    }
    float sum = (sf[0] + sf[1]) + (sf[2] + sf[3]);
    sum += __shfl_xor(sum, 16);
    sum += __shfl_xor(sum, 32);
    if (skip){
      l_run += sum;
    } else {
      float alpha = exp2f(m_run - mn);
      l_run = l_run * alpha + sum;
      m_run = mn;
      #pragma unroll
      for (int r = 0; r < 4; ++r){
        float ar = __shfl(alpha, (lane & 48) | ((g * 4 + r) & 15));
        #pragma unroll
        for (int df = 0; df < 8; ++df) o[df][r] *= ar;
      }
    }
    // pack P^T (k-consecutive reg pairs) -> bf16 u32s
    u32 pk[4][2];
    #pragma unroll
    for (int nf = 0; nf < 4; ++nf){
      pk[nf][0] = (u32)f2b(st[nf][0]) | ((u32)f2b(st[nf][1]) << 16);
      pk[nf][1] = (u32)f2b(st[nf][2]) | ((u32)f2b(st[nf][3]) << 16);
    }
    // rebuild PV A-frag: lane (g,lo) needs P[q=lo][k=kk2*32+8g .. +7]
    //   j=0..3 from src lane (lane&16)*2+(lane&15), j=4..7 from +16 lanes,
    //   frag nf = 2*kk2 + (lane>=32)
    #pragma unroll
    for (int kk2 = 0; kk2 < 2; ++kk2){
      u32 a0 = (u32)__builtin_amdgcn_ds_bpermute(srcA, (int)pk[2*kk2][0]);
      u32 b0 = (u32)__builtin_amdgcn_ds_bpermute(srcA, (int)pk[2*kk2+1][0]);
      u32 a1 = (u32)__builtin_amdgcn_ds_bpermute(srcA, (int)pk[2*kk2][1]);
      u32 b1 = (u32)__builtin_amdgcn_ds_bpermute(srcA, (int)pk[2*kk2+1][1]);
      u32 a2 = (u32)__builtin_amdgcn_ds_bpermute(srcB, (int)pk[2*kk2][0]);
      u32 b2 = (u32)__builtin_amdgcn_ds_bpermute(srcB, (int)pk[2*kk2+1][0]);
      u32 a3 = (u32)__builtin_amdgcn_ds_bpermute(srcB, (int)pk[2*kk2][1]);
      u32 b3 = (u32)__builtin_amdgcn_ds_bpermute(srcB, (int)pk[2*kk2+1][1]);
      union { u32 u[4]; bf16x8 v; } pf;
      pf.u[0] = hi ? b0 : a0;
      pf.u[1] = hi ? b1 : a1;
      pf.u[2] = hi ? b2 : a2;
      pf.u[3] = hi ? b3 : a3;
      #pragma unroll
      for (int df = 0; df < 8; ++df){
        bf16x8 vf = *(const bf16x8*)&Vs[(df * 16 + lo) * 72 + kk2 * 32 + g * 8];
        o[df] = MFMA16(pf.v, vf, o[df]);
      }
    }
    __syncthreads();
  }
  // epilogue: divide by l (stats live at lane lo = qrow%16), write bf16
  #pragma unroll
  for (int r = 0; r < 4; ++r){
    float lr = __shfl(l_run, (lane & 48) | ((g * 4 + r) & 15));
    float rl = 1.0f / lr;
    int row = q0 + w * 16 + g * 4 + r;
    #pragma unroll
    for (int df = 0; df < 8; ++df){
      float ov = o[df][r] * rl;
      ao[((size_t)(b * T_ + row)) * HD_ + h * D_ + df * 16 + lo] = f2b(ov);
    }
  }
}

// ---------------------------------------------------------------------------
extern "C" void kernel_launch(void* const* d_in, const int* in_sizes, int n_in,
                              void* d_out, int out_size, void* d_ws, size_t ws_size,
                              hipStream_t stream) {
  (void)in_sizes; (void)n_in; (void)out_size; (void)ws_size;
  const float* x    = (const float*)d_in[0];
  const float* cosp = (const float*)d_in[1];
  const float* sinp = (const float*)d_in[2];
  const int*   mask = (const int*)d_in[3];
  const float* Wq   = (const float*)d_in[4];
  const float* bq   = (const float*)d_in[5];
  const float* Wk   = (const float*)d_in[6];
  const float* bk   = (const float*)d_in[7];
  const float* Wv   = (const float*)d_in[8];
  const float* bv   = (const float*)d_in[9];
  const float* gq   = (const float*)d_in[10];
  const float* gk   = (const float*)d_in[11];
  const float* Wo   = (const float*)d_in[12];

  char* ws = (char*)d_ws;
  const size_t MB = 1024 * 1024;
  u16*   XB    = (u16*)(ws);                 // 32MB  x as bf16 [8192][2048]
  u16*   WQKVT = (u16*)(ws + 32  * MB);      // 16MB  [Wq;Wk;Wv]^T bf16 [4096][2048]
  u16*   WOT   = (u16*)(ws + 48  * MB);      //  8MB  Wo^T bf16 [2048][2048]
  u16*   QKV   = (u16*)(ws + 56  * MB);      // 64MB  qkv bf16 [8192][4096]
  u16*   QROT  = (u16*)(ws + 120 * MB);      // 32MB  q rot bf16 [B][H][T][D]
  u16*   KROT  = (u16*)(ws + 152 * MB);      // 16MB  k rot bf16 [B][HKV][T][D]
  u16*   VT    = (u16*)(ws + 168 * MB);      // 16MB  v^T bf16 [B][HKV][D][T]
  u16*   AO    = (u16*)(ws + 184 * MB);      // 32MB  attn out bf16 [8192][2048]
  float* BIAS  = (float*)(ws + 216 * MB);    // 16KB
  int*   LENS  = (int*)(ws + 216 * MB + 65536);

  k_convx<<<16384, 256, 0, stream>>>(x, XB);
  k_wtrans<<<dim3(32, 32), 256, 0, stream>>>(Wq, WQKVT, C_, HD_);
  k_wtrans<<<dim3(16, 32), 256, 0, stream>>>(Wk, WQKVT + (size_t)HD_ * C_, C_, KVD_);
  k_wtrans<<<dim3(16, 32), 256, 0, stream>>>(Wv, WQKVT + (size_t)(HD_ + KVD_) * C_, C_, KVD_);
  k_wtrans<<<dim3(32, 32), 256, 0, stream>>>(Wo, WOT, HD_, C_);
  k_prep<<<16, 256, 0, stream>>>(bq, bk, bv, BIAS);
  k_lens<<<4, 256, 0, stream>>>(mask, LENS);

  // qkv = x @ [Wq|Wk|Wv] + bias   (bf16 out)
  k_gemm<false><<<dim3(NQKV_ / 128, BT_ / 128), 256, 0, stream>>>(XB, WQKVT, BIAS, QKV, BT_, NQKV_, C_);
  // RMSNorm + mRoPE, repack q/k (q pre-scaled for exp2 softmax)
  k_rmsrope<<<BT_, 256, 0, stream>>>(QKV, cosp, sinp, mask, gq, gk, QROT, KROT);
  // v -> v^T (masked)
  k_vtrans<<<dim3(T_ / 64, D_ / 64, B_ * HKV_), 256, 0, stream>>>(QKV, mask, VT);
  // causal GQA flash attention (1-D grid, XCD-aware decode)
  k_attn<<<2048, 256, 0, stream>>>(QROT, KROT, VT, LENS, AO);
  // out = AO @ Wo   (fp32 out)
  k_gemm<true><<<dim3(C_ / 128, BT_ / 128), 256, 0, stream>>>(AO, WOT, nullptr, d_out, BT_, C_, HD_);
}